// Round 3
// baseline (176.692 us; speedup 1.0000x reference)
//
#include <hip/hip_runtime.h>
#include <cmath>

#ifndef M_PI
#define M_PI 3.14159265358979323846
#endif

// Problem constants (fixed by setup_inputs in the reference)
#define B_ 8
#define F_ 3
#define H_ 224
#define W_ 224
#define T_ 8          // ntau
#define A_ 12         // num_angles
#define NK 96         // T_*A_
#define STRIDE_ 2
#define HS_ 112
#define WS_ 112
#define PLANE_ (H_ * W_)        // 50176
#define SLICE_ (HS_ * WS_)      // 12544

// R3 structure change (discriminating experiment): no LDS, no banding.
// Block = one (bf, k) output slice -> 50 KB FULLY CONTIGUOUS stores
// (49 exact iterations of 256 threads; 12544 = 49*256).
// Bilinear taps gathered straight from global: input is 4.8 MB total and,
// with the bijective XCD swizzle below (2304 = 8 XCDs x 288 blocks, each
// XCD owns exactly 3 bf-planes = 600 KB), gathers are L2-resident.
// This removes the 448 B / 50 KB-stride store scatter that R0/R2 shared —
// the prime suspect for the residual ~63 us (T1). If dur_us doesn't move,
// the harness floor theory (T2) is confirmed.

struct LPArgs {
    int   cy[NK];  int cx[NK];
    float fy[NK];  float fx[NK];
};

static LPArgs make_args() {
    LPArgs r;
    double c = pow(60.0, 1.0 / 7.0) - 1.0;
    for (int t = 0; t < T_; ++t) {
        double tau = pow(1.0 + c, (double)t);
        for (int a = 0; a < A_; ++a) {
            double th = (double)a * (2.0 * M_PI / (double)A_) - M_PI;
            float yo = (float)(tau * sin(th)), xo = (float)(tau * cos(th));
            int k = t * A_ + a;          // natural order: out k = t*A + a
            float yf = floorf(yo), xf = floorf(xo);
            r.cy[k] = (int)yf; r.fy[k] = yo - yf;
            r.cx[k] = (int)xf; r.fx[k] = xo - xf;
        }
    }
    return r;
}

// Per-offset (vs per-element f32) floor/frac is continuity-safe: validated
// in prior rounds, absmax 1.6e-2 << 9.3e-2. Weight/clamp scheme matches the
// reference exactly: tap masked to 0 when its row/col is outside [0,224).
__global__ __launch_bounds__(256) void lp_gather_kernel(
    const float* __restrict__ inp, float* __restrict__ out, LPArgs args) {

    // Bijective XCD-aware swizzle: hardware round-robins blockIdx%8 across
    // XCDs; remap so XCD x owns contiguous chunk [x*288, (x+1)*288) =
    // 3 full bf-planes -> per-XCD L2-resident input (600 KB << 4 MB).
    const int blk = (int)blockIdx.x;              // 0..2303
    const int swz = (blk & 7) * 288 + (blk >> 3); // bijective (2304 % 8 == 0)
    const int bf  = swz / 96;                     // 0..23  (b*F + f)
    const int k   = swz - bf * 96;                // 0..95  (t*A + a)

    const int   cy = args.cy[k];  const int   cx = args.cx[k];
    const float fy = args.fy[k];  const float fx = args.fx[k];
    const float omfy = 1.0f - fy, omfx = 1.0f - fx;

    const float* plane  = inp + (size_t)bf * PLANE_;
    float*       op     = out + ((size_t)bf * NK + k) * SLICE_ + threadIdx.x;

    // m = threadIdx.x + it*256; i = m/112, j = m%112, maintained incrementally.
    int i = (int)threadIdx.x / 112;               // 0..2
    int j = (int)threadIdx.x - i * 112;

#pragma unroll 1
    for (int it = 0; it < 49; ++it) {
        const int y0 = 2 * i + cy;                // [-60, 281]
        const int x0 = 2 * j + cx;

        // Reference semantics: tap contributes iff its index is in range.
        const float mA = (y0 >= 0  && y0 <  H_    ) ? omfy : 0.0f;
        const float mB = (y0 >= -1 && y0 <  H_ - 1) ? fy   : 0.0f;
        const float wA = (x0 >= 0  && x0 <  W_    ) ? omfx : 0.0f;
        const float wB = (x0 >= -1 && x0 <  W_ - 1) ? fx   : 0.0f;

        const int ya = min(max(y0,     0), H_ - 1);
        const int yb = min(max(y0 + 1, 0), H_ - 1);
        const int xa = min(max(x0,     0), W_ - 1);
        const int xb = min(max(x0 + 1, 0), W_ - 1);

        const float* rA = plane + ya * W_;        // L1/L2-resident gathers
        const float* rB = plane + yb * W_;
        const float g00 = rA[xa], g01 = rA[xb];
        const float g10 = rB[xa], g11 = rB[xb];

        const float rr = mA * (wA * g00 + wB * g01)
                       + mB * (wA * g10 + wB * g11);

        *op = rr;                                 // contiguous 1 KB per wave
        op += 256;

        // advance m by 256: 256 = 2*112 + 32
        j += 32; i += 2;
        if (j >= 112) { j -= 112; ++i; }
    }
}

extern "C" void kernel_launch(void* const* d_in, const int* in_sizes, int n_in,
                              void* d_out, int out_size, void* d_ws, size_t ws_size,
                              hipStream_t stream) {
    const float* inp = (const float*)d_in[0];
    float*       out = (float*)d_out;

    static const LPArgs args = make_args();   // host-side, once; capture-safe

    lp_gather_kernel<<<dim3(B_ * F_ * NK), 256, 0, stream>>>(inp, out, args);
}

// Round 5
// 138.467 us; speedup vs baseline: 1.2761x; 1.2761x over previous
//
#include <hip/hip_runtime.h>
#include <cmath>
#include <algorithm>

#ifndef M_PI
#define M_PI 3.14159265358979323846
#endif

// Problem constants (fixed by setup_inputs in the reference)
#define B_ 8
#define F_ 3
#define H_ 224
#define W_ 224
#define T_ 8          // ntau
#define A_ 12         // num_angles
#define NK 96         // T_*A_
#define HS_ 112
#define WS_ 112
#define PLANE_ (H_ * W_)        // 50176
#define SLICE_ (HS_ * WS_)      // 12544

// R5 == R4 resubmit (container infra flake, like R1; kernel re-audited:
// worst group cy-range = 31 -> band 87 <= 91; LDS reads max 20383 < 20384;
// all global accesses in range).
//
// Structure: block = (bf, k-octet, i-quarter).
//  - 8 k's grouped by sorted cy -> input row-band <= 87 rows fits LDS.
//  - wave-task = (k, column-half): 28 consecutive output rows of ONE k
//    -> 12.5 KB contiguous store stream per task (R0/R2 had 3.5 KB bursts;
//       their invariant 34.9 us vs structure changes fingered the stores),
//    and per-task x-side setup amortized over 28 rows (was 8).
//  - staging total 1152 x ~80 KB = 90 MB L2 reads (R3 proved input is
//    cache-resident; its 78 us showed direct stride-2 gathers are the
//    WRONG way to read it -> back to coalesced float4 staging).
#define KG 8          // k's per group (cy-sorted)
#define NG 12         // groups
#define RI 28         // output rows per block (quarter slice)
#define NIQ 4
#define BANDROWS 91   // 2*(RI-1) + max group cy-range (31) + 2 = 87 (<=91)
#define PITCH 224     // LDS row pitch in dwords: E[0..111] | O[0..111]
#define HALF 112

// Per-offset constants (host, f64). korig maps sorted slot -> output k.
// Per-offset (vs per-element f32) floor/frac is continuity-safe: validated
// in prior rounds, absmax 1.6e-2 << 9.3e-2.
struct LPArgs {
    int   cy[NK];  int cx[NK];
    float fy[NK];  float fx[NK];
    int   korig[NK];
    int   gmin[NG]; int gmax[NG];
};

static LPArgs make_args() {
    int cy[NK], cx[NK]; float fy[NK], fx[NK];
    double c = pow(60.0, 1.0 / 7.0) - 1.0;
    for (int t = 0; t < T_; ++t) {
        double tau = pow(1.0 + c, (double)t);
        for (int a = 0; a < A_; ++a) {
            double th = (double)a * (2.0 * M_PI / (double)A_) - M_PI;
            float yo = (float)(tau * sin(th)), xo = (float)(tau * cos(th));
            int k = t * A_ + a;
            float yf = floorf(yo), xf = floorf(xo);
            cy[k] = (int)yf; fy[k] = yo - yf;
            cx[k] = (int)xf; fx[k] = xo - xf;
        }
    }
    int idx[NK];
    for (int k = 0; k < NK; ++k) idx[k] = k;
    std::sort(idx, idx + NK, [&](int a, int b) { return cy[a] < cy[b]; });
    LPArgs r;
    for (int g = 0; g < NG; ++g) { r.gmin[g] = 1000; r.gmax[g] = -1000; }
    for (int p = 0; p < NK; ++p) {
        int k = idx[p], g = p / KG;
        r.cy[p] = cy[k]; r.cx[p] = cx[k];
        r.fy[p] = fy[k]; r.fx[p] = fx[k];
        r.korig[p] = k;
        r.gmin[g] = std::min(r.gmin[g], cy[k]);
        r.gmax[g] = std::max(r.gmax[g], cy[k]);
    }
    return r;
}

// Grid 1152 = 24 bf x 12 kg x 4 iq (decoded from a bijective XCD swizzle:
// 1152 = 8 XCDs x 144; each XCD owns 3 bf-planes = 600 KB L2-resident input,
// and consecutive swz within an XCD write adjacent output regions).
// Block 1024 threads (16 waves = 8 k x 2 column-halves), LDS 79.6 KB,
// launch_bounds(1024,8) forces VGPR<=64 -> 2 blocks/CU.
//
// LDS rows are even/odd-column DEINTERLEAVED (E[0..111] | O[0..111]):
// a bilinear x-pair {ix0,ix0+1} = one even + one odd column, so both reads
// are lane-stride-1 -> conflict-free; ds_read2_b32 offset1:224 fetches the
// two y-rows of each array in one instruction.
__global__ __launch_bounds__(1024, 8) void lp_sample_kernel(
    const float* __restrict__ inp, float* __restrict__ out, LPArgs args) {

    __shared__ float lds[BANDROWS * PITCH];   // 91*224*4 = 81,536 B

    const int blk = (int)blockIdx.x;              // 0..1151
    const int swz = (blk & 7) * 144 + (blk >> 3); // bijective (1152 % 8 == 0)
    const int bf  = swz / 48;                     // 0..23
    const int rem = swz - bf * 48;
    const int kg  = rem >> 2;                     // 0..11
    const int iq  = rem & 3;                      // 0..3
    const int i0  = iq * RI;

    const int r0 = max(0, 2 * i0 + args.gmin[kg]);
    const int r1 = min(H_ - 1, 2 * i0 + 2 * (RI - 1) + args.gmax[kg] + 1);
    const int nrows = min(r1 - r0 + 1, BANDROWS);   // defensive clamp

    const float* plane = inp + (size_t)bf * PLANE_;

    {   // staging with even/odd deinterleave: float4 {e,o,e,o} -> E-pair + O-pair
        const int n = nrows * (W_ / 4);   // <= 91*56 = 5096
        for (int v = threadIdx.x; v < n; v += 1024) {
            const unsigned r = (unsigned)v / 56u;       // compiler magic-div
            const int u = v - (int)r * 56;              // float4 index in row
            const float4 val = *(const float4*)(plane + (size_t)(r0 + (int)r) * W_ + 4 * u);
            float* rowp = lds + r * PITCH;
            const int e = 2 * u;
            rowp[e]            = val.x;   // col 4u   (even)
            rowp[e + 1]        = val.z;   // col 4u+2 (even)
            rowp[HALF + e]     = val.y;   // col 4u+1 (odd)
            rowp[HALF + e + 1] = val.w;   // col 4u+3 (odd)
        }
    }
    __syncthreads();

    const int lane = threadIdx.x & 63;
    const int wave = __builtin_amdgcn_readfirstlane((int)threadIdx.x >> 6);

    // wave-task: one k (sorted slot kk), one column half. 16 waves = 8k x 2h.
    const int kk = kg * KG + (wave >> 1);
    const int h  = wave & 1;

    const int   cy = args.cy[kk]; const float fy = args.fy[kk];
    const int   cx = args.cx[kk]; const float fx = args.fx[kk];
    const int   ko = args.korig[kk];
    const int   P  = cx & 1;                      // x-pair parity (uniform)

    // --- per-task x-side setup (amortized over RI=28 rows) ---
    const int j   = h * 64 + lane;
    const int ix0 = 2 * j + cx;                   // true left column
    const float wLv = (ix0 >= 0  && ix0 <= W_ - 1) ? (1.0f - fx) : 0.0f;
    const float wRv = (ix0 >= -1 && ix0 <= W_ - 2) ? fx          : 0.0f;
    // even col = ix0+P, odd col = ix0+1-P (ix0 parity == P per lane)
    int eidx = (ix0 + P) >> 1;                    // arith shift; clamp below
    int oidx = (ix0 + 1 - P) >> 1;
    eidx = min(max(eidx, 0), HALF - 1);           // weights are 0 when clamped
    oidx = min(max(oidx, 0), HALF - 1);
    const float wE = P ? wRv : wLv;               // uniform select
    const float wO = P ? wLv : wRv;

    const float* eptr = lds + eidx;               // lane-stride-1 -> no conflicts
    const float* optr = lds + HALF + oidx;

    float* orow = out + (size_t)bf * (NK * SLICE_) + (size_t)ko * SLICE_
                      + (size_t)i0 * WS_ + j;

    if (j < WS_) {                                // mask idle lanes for whole loop
#pragma unroll 4
        for (int di = 0; di < RI; ++di) {
            const int iy0 = 2 * (i0 + di) + cy;   // wave-uniform
            float mA, mB;                          // slot-shifting clamp scheme:
            if (iy0 >= 0 && iy0 <= H_ - 2)  { mA = 1.0f - fy; mB = fy; }
            else if (iy0 == -1)             { mA = fy;        mB = 0.0f; }
            else if (iy0 == H_ - 1)         { mA = 0.0f;      mB = 1.0f - fy; }
            else                            { mA = 0.0f;      mB = 0.0f; }
            const int by = min(max(iy0, 0), H_ - 2);      // rows {by,by+1} staged
            const int rb = min(by - r0, BANDROWS - 2) * PITCH;  // uniform

            // ds_read2_b32 offset0:0 offset1:224 x2 (conflict-free)
            const float e0 = eptr[rb], e1 = eptr[rb + PITCH];
            const float o0 = optr[rb], o1 = optr[rb + PITCH];

            const float rr = wE * (mA * e0 + mB * e1)
                           + wO * (mA * o0 + mB * o1);

            orow[(size_t)di * WS_] = rr;          // 28 x 448 B contiguous per task
        }
    }
}

extern "C" void kernel_launch(void* const* d_in, const int* in_sizes, int n_in,
                              void* d_out, int out_size, void* d_ws, size_t ws_size,
                              hipStream_t stream) {
    const float* inp = (const float*)d_in[0];
    float*       out = (float*)d_out;

    static const LPArgs args = make_args();   // host-side, once; capture-safe

    lp_sample_kernel<<<dim3(24 * NG * NIQ), 1024, 0, stream>>>(inp, out, args);
}

// Round 6
// 133.909 us; speedup vs baseline: 1.3195x; 1.0340x over previous
//
#include <hip/hip_runtime.h>
#include <cmath>
#include <algorithm>

#ifndef M_PI
#define M_PI 3.14159265358979323846
#endif

// Problem constants (fixed by setup_inputs in the reference)
#define B_ 8
#define F_ 3
#define H_ 224
#define W_ 224
#define T_ 8          // ntau
#define A_ 12         // num_angles
#define NK 96         // T_*A_
#define HS_ 112
#define WS_ 112
#define PLANE_ (H_ * W_)        // 50176
#define SLICE_ (HS_ * WS_)      // 12544

// R6: full-row wave-tasks + dwordx2 stores + 4-phase LDS.
// Evidence so far: kernel time 34.9 us is INVARIANT to bank conflicts,
// staging volume, and store contiguity (R0=R2=34.9; R5 contiguous = 40.1).
// The untouched lever: wave-iteration count and store-instruction count
// (all prior variants: 1 dword/lane, half-row tasks). Here each lane
// computes 2 adjacent output columns and stores ONE dwordx2; a wave-task
// covers a full 448 B output row (56 active lanes). Wave-iters and store
// instrs halve; LDS instr count unchanged.
//
// 4-phase LDS layout (col mod 4): row r = [P0[0..55]|pad|P1|pad|P2|pad|P3|pad],
// phase p holds input col 4u+p at index u, row pitch 228 dwords.
// The 4 taps of an output pair {2l, 2l+1} are cols 4l+cx+t (t=0..3) = one
// col from EACH phase at index l + ((cx+t)>>2): uniform offset per tap,
// lane-stride-1 -> conflict-free (56 lanes over 32 banks = 2-way = free).
// float4 staging maps perfectly: val.{x,y,z,w} -> P{0,1,2,3}[u].
#define RI 8          // output rows per block
#define BANDROWS 78   // 2*(RI-1) + group cy-range (59) + 2 = 75 (<=78)
#define PH 57         // phase pitch (56 + 1 pad)
#define PITCH 228     // row pitch = 4*PH
#define NLANE 56      // active lanes per row-task

struct LPArgs {
    int   cy[NK];  int cx[NK];
    float fy[NK];  float fx[NK];
    int   korig[NK];
    int   cymin[2]; int cymax[2];
};

static LPArgs make_args() {
    int cy[NK], cx[NK]; float fy[NK], fx[NK];
    double c = pow(60.0, 1.0 / 7.0) - 1.0;
    for (int t = 0; t < T_; ++t) {
        double tau = pow(1.0 + c, (double)t);
        for (int a = 0; a < A_; ++a) {
            double th = (double)a * (2.0 * M_PI / (double)A_) - M_PI;
            float yo = (float)(tau * sin(th)), xo = (float)(tau * cos(th));
            int k = t * A_ + a;
            float yf = floorf(yo), xf = floorf(xo);
            cy[k] = (int)yf; fy[k] = yo - yf;
            cx[k] = (int)xf; fx[k] = xo - xf;
        }
    }
    int idx[NK];
    for (int k = 0; k < NK; ++k) idx[k] = k;
    std::sort(idx, idx + NK, [&](int a, int b) { return cy[a] < cy[b]; });
    LPArgs r;
    r.cymin[0] = r.cymin[1] = 1000; r.cymax[0] = r.cymax[1] = -1000;
    for (int p = 0; p < NK; ++p) {
        int k = idx[p], g = p / 48;
        r.cy[p] = cy[k]; r.cx[p] = cx[k];
        r.fy[p] = fy[k]; r.fx[p] = fx[k];
        r.korig[p] = k;
        r.cymin[g] = std::min(r.cymin[g], cy[k]);
        r.cymax[g] = std::max(r.cymax[g], cy[k]);
    }
    return r;
}

// Grid (24 bf, 14 i-tiles, 2 cy-groups) = 672 blocks — the tied-best R2
// skeleton. Block 1024 (16 waves); tasks = 48 k's x full row -> 3 tt iters.
// LDS 78*228*4 = 71,136 B; launch_bounds(1024,8) -> VGPR<=64, 2 blocks/CU.
__global__ __launch_bounds__(1024, 8) void lp_sample_kernel(
    const float* __restrict__ inp, float* __restrict__ out, LPArgs args) {

    __shared__ float lds[BANDROWS * PITCH];   // 71,136 B

    const int bf = blockIdx.x;            // b*F + f
    const int i0 = blockIdx.y * RI;
    const int g  = blockIdx.z;

    const int r0 = max(0, 2 * i0 + args.cymin[g]);
    const int r1 = min(H_ - 1, 2 * i0 + 2 * (RI - 1) + args.cymax[g] + 1);
    const int nrows = min(r1 - r0 + 1, BANDROWS);   // defensive clamp

    const float* plane = inp + (size_t)bf * PLANE_;

    {   // staging: float4 {c,c+1,c+2,c+3} -> one slot in each of 4 phases
        const int n = nrows * (W_ / 4);   // <= 78*56 = 4368
        for (int v = threadIdx.x; v < n; v += 1024) {
            const unsigned r = (unsigned)v / 56u;       // compiler magic-div
            const int u = v - (int)r * 56;              // float4 index in row
            const float4 val = *(const float4*)(plane + (size_t)(r0 + (int)r) * W_ + 4 * u);
            float* rowp = lds + r * PITCH + u;
            rowp[0 * PH] = val.x;   // col 4u   (phase 0)
            rowp[1 * PH] = val.y;   // col 4u+1 (phase 1)
            rowp[2 * PH] = val.z;   // col 4u+2 (phase 2)
            rowp[3 * PH] = val.w;   // col 4u+3 (phase 3)
        }
    }
    __syncthreads();

    const int lane = threadIdx.x & 63;
    const int wave = __builtin_amdgcn_readfirstlane((int)threadIdx.x >> 6);

    float* outp = out + (size_t)bf * (NK * SLICE_) + (size_t)i0 * WS_;
    const bool act = (lane < NLANE);

#pragma unroll 1
    for (int tt = 0; tt < 3; ++tt) {
        const int kk = g * 48 + wave + (tt << 4);     // sorted slot, 0..95

        const int   cy = args.cy[kk]; const float fy = args.fy[kk];
        const int   cx = args.cx[kk]; const float fx = args.fx[kk];
        const int   ko = args.korig[kk];
        const float omfx = 1.0f - fx;

        // --- per-task setup (amortized over RI=8 rows) ---
        // lane l -> output cols {2l, 2l+1}; taps = input cols 4l+cx+t, t=0..3
        // tap t lives in phase (cx+t)&3 at index l + ((cx+t)>>2).
        const int l = lane;
        const float* tp[4];
        float tw[4];
#pragma unroll
        for (int t = 0; t < 4; ++t) {
            const int s   = cx + t;                   // uniform
            const int ct  = 4 * l + s;                // tap column
            const int ph  = s & 3;                    // uniform phase
            int idx = l + (s >> 2);                   // arith shift (s may be <0)
            idx = min(max(idx, 0), NLANE - 1);        // weight 0 when clamped
            tp[t] = lds + ph * PH + idx;
            const float wbase = (t & 1) ? fx : omfx;  // t0,t2: left tap; t1,t3: right
            tw[t] = (ct >= 0 && ct < W_) ? wbase : 0.0f;
        }

        float2* orow = (float2*)(outp + (size_t)ko * SLICE_) + l;   // col 2l

        if (act) {
#pragma unroll 2
            for (int di = 0; di < RI; ++di) {
                const int iy0 = 2 * (i0 + di) + cy;   // wave-uniform
                float mA, mB;
                if (iy0 >= 0 && iy0 <= H_ - 2)  { mA = 1.0f - fy; mB = fy; }
                else if (iy0 == -1)             { mA = fy;        mB = 0.0f; }
                else if (iy0 == H_ - 1)         { mA = 0.0f;      mB = 1.0f - fy; }
                else                            { mA = 0.0f;      mB = 0.0f; }
                const int by = min(max(iy0, 0), H_ - 2);      // rows {by,by+1}
                const int rb = min(by - r0, BANDROWS - 2) * PITCH;  // uniform

                // 4x ds_read2_b32 offset0:0 offset1:228 (conflict-free)
                const float a0 = tp[0][rb], a1 = tp[0][rb + PITCH];
                const float b0 = tp[1][rb], b1 = tp[1][rb + PITCH];
                const float c0 = tp[2][rb], c1 = tp[2][rb + PITCH];
                const float d0 = tp[3][rb], d1 = tp[3][rb + PITCH];

                float2 rr;
                rr.x = mA * (tw[0] * a0 + tw[1] * b0)
                     + mB * (tw[0] * a1 + tw[1] * b1);
                rr.y = mA * (tw[2] * c0 + tw[3] * d0)
                     + mB * (tw[2] * c1 + tw[3] * d1);

                orow[(size_t)di * (WS_ / 2)] = rr;    // dwordx2, 448 B/row/wave
            }
        }
    }
}

extern "C" void kernel_launch(void* const* d_in, const int* in_sizes, int n_in,
                              void* d_out, int out_size, void* d_ws, size_t ws_size,
                              hipStream_t stream) {
    const float* inp = (const float*)d_in[0];
    float*       out = (float*)d_out;

    static const LPArgs args = make_args();   // host-side, once; capture-safe

    lp_sample_kernel<<<dim3(B_ * F_, HS_ / RI, 2), 1024, 0, stream>>>(inp, out, args);
}